// Round 1
// 202.801 us; speedup vs baseline: 1.2260x; 1.2260x over previous
//
#include <hip/hip_runtime.h>
#include <hip/hip_bf16.h>
#include <float.h>

// Problem constants (from setup_inputs): B=16, N=21504, C=80, G=64, K=9
#define BB 16
#define NN 21504
#define CC 80
#define GG 64
#define KK 9
#define NSEG 4
#define SEG4 (NN / 2 / NSEG)   // float4s per segment: 2688
#define T4   (SEG4 / 64)       // 42 float4 iterations per lane

// focal grid: 3360 blocks * 256 threads * 8 float4 = 6,881,280 = B*N*C/4 exactly
#define FB 3360
#define FSTRIDE (FB * 256)
#define TOPKB (BB * GG)        // 1024 top-k blocks in the fused kernel

// ---------------- focal helpers ----------------
__device__ __forceinline__ float focal_t0(float x) {
    float ax = fabsf(x);
    float em = __expf(-ax);
    float sp = __logf(1.0f + em);
    float spx = fmaxf(x, 0.0f) + sp;     // softplus(x)
    float r = 1.0f / (1.0f + em);
    float p = (x >= 0.0f) ? r : em * r;  // sigmoid(x)
    return 0.75f * spx * p * p;
}

__device__ __forceinline__ float focal_corr(float x) {
    float ax = fabsf(x);
    float em = __expf(-ax);
    float sp = __logf(1.0f + em);
    float spx = fmaxf(x, 0.0f) + sp;
    float spn = fmaxf(-x, 0.0f) + sp;
    float r = 1.0f / (1.0f + em);
    float p = (x >= 0.0f) ? r : em * r;
    float q = 1.0f - p;
    float f1 = 0.25f * spn * q * q;
    float f0 = 0.75f * spx * p * p;
    return f1 - f0;
}

// one shared distance function so both scans produce bit-identical values
__device__ __forceinline__ float d2f(float cx, float cy, float x, float y) {
    float dx = cx - x, dy = cy - y;
    return dx * dx + dy * dy;
}

// Kernel 1 (FUSED): blocks [0,1024) = per-segment top-9 (one wave per
// (pair,segment)); blocks [1024,4384) = focal main sum, writing per-block
// partials (NO atomics — the 3360 single-address f64 atomics were a
// contended-line tail). The two roles are independent; HBM-bound focal
// overlaps L2-bound top-k.
__global__ __launch_bounds__(256) void k1_seg_focal(
    const float* __restrict__ locations,   // (N,2)
    const float* __restrict__ gt_boxes,    // (B,G,4)
    const float* __restrict__ logits,      // (B,N,C)
    float* __restrict__ cand_d,            // (1024*NSEG*KK)
    int*   __restrict__ cand_n,
    unsigned long long* __restrict__ hdr,  // 64B header: acc[3] + ticket
    double* __restrict__ focal_part)       // (FB) per-block partial sums
{
    if (blockIdx.x >= TOPKB) {
        // ---------------- focal role ----------------
        int fb = (int)blockIdx.x - TOPKB;
        const float4* v = (const float4*)logits;
        int tid = fb * 256 + threadIdx.x;

        float4 L0 = v[tid + 0 * FSTRIDE];
        float4 L1 = v[tid + 1 * FSTRIDE];
        float4 L2 = v[tid + 2 * FSTRIDE];
        float4 L3 = v[tid + 3 * FSTRIDE];
        float4 L4 = v[tid + 4 * FSTRIDE];
        float4 L5 = v[tid + 5 * FSTRIDE];
        float4 L6 = v[tid + 6 * FSTRIDE];
        float4 L7 = v[tid + 7 * FSTRIDE];

        float s0 = 0.f, s1 = 0.f, s2 = 0.f, s3 = 0.f;
        s0 += focal_t0(L0.x); s1 += focal_t0(L0.y); s2 += focal_t0(L0.z); s3 += focal_t0(L0.w);
        s0 += focal_t0(L1.x); s1 += focal_t0(L1.y); s2 += focal_t0(L1.z); s3 += focal_t0(L1.w);
        s0 += focal_t0(L2.x); s1 += focal_t0(L2.y); s2 += focal_t0(L2.z); s3 += focal_t0(L2.w);
        s0 += focal_t0(L3.x); s1 += focal_t0(L3.y); s2 += focal_t0(L3.z); s3 += focal_t0(L3.w);
        s0 += focal_t0(L4.x); s1 += focal_t0(L4.y); s2 += focal_t0(L4.z); s3 += focal_t0(L4.w);
        s0 += focal_t0(L5.x); s1 += focal_t0(L5.y); s2 += focal_t0(L5.z); s3 += focal_t0(L5.w);
        s0 += focal_t0(L6.x); s1 += focal_t0(L6.y); s2 += focal_t0(L6.z); s3 += focal_t0(L6.w);
        s0 += focal_t0(L7.x); s1 += focal_t0(L7.y); s2 += focal_t0(L7.z); s3 += focal_t0(L7.w);

        double d = (double)((s0 + s1) + (s2 + s3));
#pragma unroll
        for (int o = 32; o > 0; o >>= 1) d += __shfl_down(d, o);
        __shared__ double wsum[4];
        if ((threadIdx.x & 63) == 0) wsum[threadIdx.x >> 6] = d;
        __syncthreads();
        if (threadIdx.x == 0)
            focal_part[fb] = wsum[0] + wsum[1] + wsum[2] + wsum[3];
        return;
    }

    // ---------------- top-k segment role ----------------
    if (blockIdx.x == 0 && threadIdx.x < 8) hdr[threadIdx.x] = 0ull;

    int seg  = threadIdx.x >> 6;           // 0..3
    int lane = threadIdx.x & 63;
    int pair = blockIdx.x;                 // 0..1023
    int b = pair >> 6;
    int g = pair & (GG - 1);

    const float4 gt = ((const float4*)gt_boxes)[b * GG + g];
    float cx = gt.x, cy = gt.y;
    const float4* loc4 = (const float4*)locations;
    int base4 = seg * SEG4 + lane;

    // Scan 1: per-lane min over 84 points; 6 groups of 7 batched loads
    float m0 = FLT_MAX, m1 = FLT_MAX, m2 = FLT_MAX, m3 = FLT_MAX;
    for (int t = 0; t < T4; t += 7) {
        float4 L0 = loc4[base4 + (t + 0) * 64];
        float4 L1 = loc4[base4 + (t + 1) * 64];
        float4 L2 = loc4[base4 + (t + 2) * 64];
        float4 L3 = loc4[base4 + (t + 3) * 64];
        float4 L4 = loc4[base4 + (t + 4) * 64];
        float4 L5 = loc4[base4 + (t + 5) * 64];
        float4 L6 = loc4[base4 + (t + 6) * 64];
        m0 = fminf(m0, fminf(d2f(cx, cy, L0.x, L0.y), d2f(cx, cy, L0.z, L0.w)));
        m1 = fminf(m1, fminf(d2f(cx, cy, L1.x, L1.y), d2f(cx, cy, L1.z, L1.w)));
        m2 = fminf(m2, fminf(d2f(cx, cy, L2.x, L2.y), d2f(cx, cy, L2.z, L2.w)));
        m3 = fminf(m3, fminf(d2f(cx, cy, L3.x, L3.y), d2f(cx, cy, L3.z, L3.w)));
        m0 = fminf(m0, fminf(d2f(cx, cy, L4.x, L4.y), d2f(cx, cy, L4.z, L4.w)));
        m1 = fminf(m1, fminf(d2f(cx, cy, L5.x, L5.y), d2f(cx, cy, L5.z, L5.w)));
        m2 = fminf(m2, fminf(d2f(cx, cy, L6.x, L6.y), d2f(cx, cy, L6.z, L6.w)));
    }
    float md = fminf(fminf(m0, m1), fminf(m2, m3));

    // T = 9th-smallest lane-min (ties only enlarge T -> superset, safe)
    float v = md;
    float T = FLT_MAX;
    for (int r = 0; r < KK; ++r) {
        float m = v;
        for (int s = 1; s < 64; s <<= 1) m = fminf(m, __shfl_xor(m, s));
        T = m;
        if (v == m) v = FLT_MAX;
    }

    // Scan 2: collect candidates d2 <= T, up to 6 per lane in named scalars
    float sd0 = FLT_MAX, sd1 = FLT_MAX, sd2 = FLT_MAX,
          sd3 = FLT_MAX, sd4 = FLT_MAX, sd5 = FLT_MAX;
    int   sn0 = 0x7fffffff, sn1 = 0x7fffffff, sn2 = 0x7fffffff,
          sn3 = 0x7fffffff, sn4 = 0x7fffffff, sn5 = 0x7fffffff;
    int cnt = 0;
#define PUSH(dv, nv)                                             \
    do {                                                         \
        if (cnt == 0)      { sd0 = dv; sn0 = nv; }               \
        else if (cnt == 1) { sd1 = dv; sn1 = nv; }               \
        else if (cnt == 2) { sd2 = dv; sn2 = nv; }               \
        else if (cnt == 3) { sd3 = dv; sn3 = nv; }               \
        else if (cnt == 4) { sd4 = dv; sn4 = nv; }               \
        else if (cnt == 5) { sd5 = dv; sn5 = nv; }               \
        ++cnt;                                                   \
    } while (0)
#define TEST(Lv, tt)                                             \
    do {                                                         \
        int i4 = base4 + (tt) * 64;                              \
        float da = d2f(cx, cy, Lv.x, Lv.y);                      \
        float db = d2f(cx, cy, Lv.z, Lv.w);                      \
        if (da <= T) PUSH(da, 2 * i4);                           \
        if (db <= T) PUSH(db, 2 * i4 + 1);                       \
    } while (0)

    for (int t = 0; t < T4; t += 7) {
        float4 L0 = loc4[base4 + (t + 0) * 64];
        float4 L1 = loc4[base4 + (t + 1) * 64];
        float4 L2 = loc4[base4 + (t + 2) * 64];
        float4 L3 = loc4[base4 + (t + 3) * 64];
        float4 L4 = loc4[base4 + (t + 4) * 64];
        float4 L5 = loc4[base4 + (t + 5) * 64];
        float4 L6 = loc4[base4 + (t + 6) * 64];
        TEST(L0, t + 0);
        TEST(L1, t + 1);
        TEST(L2, t + 2);
        TEST(L3, t + 3);
        TEST(L4, t + 4);
        TEST(L5, t + 5);
        TEST(L6, t + 6);
    }
#undef TEST
#undef PUSH

    int ovf = (cnt > 6) ? 1 : 0;
    for (int s = 1; s < 64; s <<= 1) ovf = max(ovf, __shfl_xor(ovf, s));

    int obase = (pair * NSEG + seg) * KK;
    if (ovf == 0) {
        for (int r = 0; r < KK; ++r) {
            float bv = sd0; int bn = sn0;
            bool c;
            c = sd1 < bv; bv = c ? sd1 : bv; bn = c ? sn1 : bn;
            c = sd2 < bv; bv = c ? sd2 : bv; bn = c ? sn2 : bn;
            c = sd3 < bv; bv = c ? sd3 : bv; bn = c ? sn3 : bn;
            c = sd4 < bv; bv = c ? sd4 : bv; bn = c ? sn4 : bn;
            c = sd5 < bv; bv = c ? sd5 : bv; bn = c ? sn5 : bn;
            for (int s = 1; s < 64; s <<= 1) {
                float ov = __shfl_xor(bv, s);
                int   on = __shfl_xor(bn, s);
                bool cc = (ov < bv) || (ov == bv && on < bn);
                bv = cc ? ov : bv;
                bn = cc ? on : bn;
            }
            if (sn0 == bn) sd0 = FLT_MAX;
            if (sn1 == bn) sd1 = FLT_MAX;
            if (sn2 == bn) sd2 = FLT_MAX;
            if (sn3 == bn) sd3 = FLT_MAX;
            if (sn4 == bn) sd4 = FLT_MAX;
            if (sn5 == bn) sd5 = FLT_MAX;
            if (lane == 0) { cand_d[obase + r] = bv; cand_n[obase + r] = bn; }
        }
    } else {
        // rare exact fallback: 9 lex-min rescans of this segment
        float lastD = -1.0f; int lastN = -1;
        for (int r = 0; r < KK; ++r) {
            float bv = FLT_MAX; int bn = 0x7fffffff;
            for (int t = 0; t < T4; ++t) {
                int i4 = base4 + t * 64;
                float4 A = loc4[i4];
                float da = d2f(cx, cy, A.x, A.y);
                float db = d2f(cx, cy, A.z, A.w);
                int na = 2 * i4, nb = 2 * i4 + 1;
                bool ga = (da > lastD) || (da == lastD && na > lastN);
                bool ca = ga && ((da < bv) || (da == bv && na < bn));
                bv = ca ? da : bv; bn = ca ? na : bn;
                bool gb = (db > lastD) || (db == lastD && nb > lastN);
                bool cb = gb && ((db < bv) || (db == bv && nb < bn));
                bv = cb ? db : bv; bn = cb ? nb : bn;
            }
            for (int s = 1; s < 64; s <<= 1) {
                float ov = __shfl_xor(bv, s);
                int   on = __shfl_xor(bn, s);
                bool cc = (ov < bv) || (ov == bv && on < bn);
                bv = cc ? ov : bv;
                bn = cc ? on : bn;
            }
            lastD = bv; lastN = bn;
            if (lane == 0) { cand_d[obase + r] = bv; cand_n[obase + r] = bn; }
        }
    }
}

// Kernel 2: one wave per pair merges 36 candidates (one per lane),
// extracts the global top-9 and does the bbox L1 + GIoU epilogue.
// v2: writes per-BLOCK partials (no atomics; acc[1]/acc[2] shared a cache
// line with acc[0] -> 512 contended cross-XCD f64 atomics removed).
__global__ __launch_bounds__(256) void topk_merge_kernel(
    const float* __restrict__ pred_boxes,  // (B,N,4)
    const float* __restrict__ gt_boxes,    // (B,G,4)
    const float* __restrict__ cand_d,
    const int*   __restrict__ cand_n,
    int* __restrict__ sel,
    double* __restrict__ merge_l1,         // (256)
    double* __restrict__ merge_gio)        // (256)
{
    int wv   = threadIdx.x >> 6;
    int lane = threadIdx.x & 63;
    int pair = blockIdx.x * 4 + wv;        // 0..1023
    int b = pair >> 6;
    int g = pair & (GG - 1);

    const float4 gt = ((const float4*)gt_boxes)[b * GG + g];

    float vd = FLT_MAX; int vn = 0x7fffffff;
    if (lane < NSEG * KK) {
        vd = cand_d[pair * NSEG * KK + lane];
        vn = cand_n[pair * NSEG * KK + lane];
    }

    int myn = 0;
    for (int r = 0; r < KK; ++r) {
        float bv = vd; int bn = vn;
        for (int s = 1; s < 64; s <<= 1) {
            float ov = __shfl_xor(bv, s);
            int   on = __shfl_xor(bn, s);
            bool cc = (ov < bv) || (ov == bv && on < bn);
            bv = cc ? ov : bv;
            bn = cc ? on : bn;
        }
        if (vn == bn) vd = FLT_MAX;   // n unique across lanes
        if (lane == r) myn = bn;
        if (lane == 0) sel[pair * KK + r] = bn;
    }
    myn = myn < 0 ? 0 : (myn >= NN ? NN - 1 : myn);  // fault guard

    float l1 = 0.0f, gio = 0.0f;
    if (lane < KK) {
        float4 p = ((const float4*)pred_boxes)[b * NN + myn];
        l1 = fabsf(p.x - gt.x) + fabsf(p.y - gt.y) + fabsf(p.z - gt.z) + fabsf(p.w - gt.w);

        float ax1 = p.x - 0.5f * p.z, ay1 = p.y - 0.5f * p.w;
        float ax2 = p.x + 0.5f * p.z, ay2 = p.y + 0.5f * p.w;
        float bx1 = gt.x - 0.5f * gt.z, by1 = gt.y - 0.5f * gt.w;
        float bx2 = gt.x + 0.5f * gt.z, by2 = gt.y + 0.5f * gt.w;

        float area_a = (ax2 - ax1) * (ay2 - ay1);
        float area_b = (bx2 - bx1) * (by2 - by1);
        float ix1 = fmaxf(ax1, bx1), iy1 = fmaxf(ay1, by1);
        float ix2 = fminf(ax2, bx2), iy2 = fminf(ay2, by2);
        float iw = fmaxf(ix2 - ix1, 0.0f), ih = fmaxf(iy2 - iy1, 0.0f);
        float inter = iw * ih;
        float uni = area_a + area_b - inter;
        float iou = inter / uni;
        float ccx1 = fminf(ax1, bx1), ccy1 = fminf(ay1, by1);
        float ccx2 = fmaxf(ax2, bx2), ccy2 = fmaxf(ay2, by2);
        float cw = fmaxf(ccx2 - ccx1, 0.0f), ch = fmaxf(ccy2 - ccy1, 0.0f);
        float ac = cw * ch;
        float giou = iou - (ac - uni) / ac;
        gio = 1.0f - giou;
    }
    for (int o = 32; o > 0; o >>= 1) {
        l1 += __shfl_down(l1, o);
        gio += __shfl_down(gio, o);
    }
    __shared__ float wl1[4], wg[4];
    if (lane == 0) { wl1[wv] = l1; wg[wv] = gio; }
    __syncthreads();
    if (threadIdx.x == 0) {
        merge_l1[blockIdx.x]  = (double)wl1[0] + (double)wl1[1] + (double)wl1[2] + (double)wl1[3];
        merge_gio[blockIdx.x] = (double)wg[0] + (double)wg[1] + (double)wg[2] + (double)wg[3];
    }
}

// Kernel 3: dedup + correction + partial-sum fold + FUSED finalize via
// device-atomic ticket. Each of the 64 blocks folds a disjoint slice of
// the focal/merge partials so the only contended atomics are 64x3.
#define EPB 144   // elements per block (576 / 4)
__global__ __launch_bounds__(256) void correction_kernel(
    const float* __restrict__ logits, const int* __restrict__ sel,
    const int* __restrict__ gt_labels, double* __restrict__ acc,
    int* __restrict__ ticket, float* __restrict__ out,
    const double* __restrict__ focal_part,
    const double* __restrict__ merge_l1,
    const double* __restrict__ merge_gio)
{
    int bq = blockIdx.x;           // 0..63
    int b  = bq >> 2;              // image
    int q  = bq & 3;               // quarter

    __shared__ int keys[GG * KK];
    for (int e = threadIdx.x; e < GG * KK; e += blockDim.x) {
        int g = e / KK;
        int n = sel[(b * GG + g) * KK + (e - g * KK)];
        keys[e] = n * CC + gt_labels[b * GG + g];
    }
    __syncthreads();

    bool active = (threadIdx.x < EPB);
    int e = q * EPB + (active ? threadIdx.x : 0);   // bounded index
    int k = keys[e];
    k = active ? k : -1;                            // -1 never matches

    // branch-free duplicate test, 8 pipelined LDS reads per group
    int dup = 0;
    for (int e2 = 0; e2 < GG * KK; e2 += 8) {
        int k0 = keys[e2 + 0];
        int k1 = keys[e2 + 1];
        int k2 = keys[e2 + 2];
        int k3 = keys[e2 + 3];
        int k4 = keys[e2 + 4];
        int k5 = keys[e2 + 5];
        int k6 = keys[e2 + 6];
        int k7 = keys[e2 + 7];
        int h = 0;
        h |= (int)(k0 == k) & (int)(e2 + 0 < e);
        h |= (int)(k1 == k) & (int)(e2 + 1 < e);
        h |= (int)(k2 == k) & (int)(e2 + 2 < e);
        h |= (int)(k3 == k) & (int)(e2 + 3 < e);
        h |= (int)(k4 == k) & (int)(e2 + 4 < e);
        h |= (int)(k5 == k) & (int)(e2 + 5 < e);
        h |= (int)(k6 == k) & (int)(e2 + 6 < e);
        h |= (int)(k7 == k) & (int)(e2 + 7 < e);
        dup |= h;
    }

    float corr = 0.0f;
    if (active && dup == 0) {
        corr = focal_corr(logits[(long long)b * NN * CC + k]);
    }

    double d = (double)corr;
    // fold this block's slice of the focal partials (entries ≡ bq mod 64):
    // 52-53 entries, one per thread, all in wave 0 (threads 0..52).
    if (threadIdx.x < 53) {
        int fb = bq + (threadIdx.x << 6);
        if (fb < FB) d += focal_part[fb];
    }
#pragma unroll
    for (int o = 32; o > 0; o >>= 1) d += __shfl_down(d, o);
    __shared__ double wsum[4];
    if ((threadIdx.x & 63) == 0) wsum[threadIdx.x >> 6] = d;
    __syncthreads();
    __shared__ int amlast;
    if (threadIdx.x == 0) {
        double s1 = 0.0, s2 = 0.0;
#pragma unroll
        for (int i = 0; i < 4; ++i) {
            s1 += merge_l1[bq * 4 + i];
            s2 += merge_gio[bq * 4 + i];
        }
        atomicAdd(&acc[0], wsum[0] + wsum[1] + wsum[2] + wsum[3]);
        atomicAdd(&acc[1], s1);
        atomicAdd(&acc[2], s2);
        __threadfence();                       // my adds visible before ticket
        int t = atomicAdd(ticket, 1);
        amlast = (t == (int)gridDim.x - 1) ? 1 : 0;
    }
    __syncthreads();
    if (threadIdx.x == 0 && amlast) {
        double a0 = atomicAdd(&acc[0], 0.0);
        double a1 = atomicAdd(&acc[1], 0.0);
        double a2 = atomicAdd(&acc[2], 0.0);
        out[0] = (float)(a0 / (double)((long long)BB * NN * CC));
        out[1] = (float)(a1 / (double)(BB * GG * KK * 4));
        out[2] = (float)(a2 / (double)(BB * GG * KK));
    }
}

extern "C" void kernel_launch(void* const* d_in, const int* in_sizes, int n_in,
                              void* d_out, int out_size, void* d_ws, size_t ws_size,
                              hipStream_t stream) {
    const float* pred_logits = (const float*)d_in[0];  // (B,N,C)
    const float* pred_boxes  = (const float*)d_in[1];  // (B,N,4)
    const float* locations   = (const float*)d_in[2];  // (N,2)
    const float* gt_boxes    = (const float*)d_in[3];  // (B,G,4)
    const int*   gt_labels   = (const int*)d_in[4];    // (B,G)
    float* out = (float*)d_out;

    // workspace layout:
    //   [0,64)          header: acc[3] doubles + ticket int + pad
    //   [64,36928)      sel        1024*9 ints
    //   [36928,184384)  candd      1024*4*9 floats
    //   [184384,331840) candn      1024*4*9 ints
    //   [331840,358720) focal_part 3360 doubles
    //   [358720,360768) merge_l1   256 doubles
    //   [360768,362816) merge_gio  256 doubles
    unsigned long long* hdr = (unsigned long long*)d_ws;
    double* acc    = (double*)d_ws;
    int*    ticket = (int*)((char*)d_ws + 24);
    int*    sel    = (int*)((char*)d_ws + 64);
    float*  candd  = (float*)((char*)d_ws + 36928);
    int*    candn  = (int*)((char*)d_ws + 184384);
    double* focal_part = (double*)((char*)d_ws + 331840);
    double* merge_l1   = (double*)((char*)d_ws + 358720);
    double* merge_gio  = (double*)((char*)d_ws + 360768);

    // K1: fused top-k segments (blocks 0..1023) + focal partials (1024..4383)
    k1_seg_focal<<<TOPKB + FB, 256, 0, stream>>>(
        locations, gt_boxes, pred_logits, candd, candn, hdr, focal_part);

    // K2: merge 36 candidates/pair + bbox epilogue -> per-block partials
    topk_merge_kernel<<<BB * GG / 4, 256, 0, stream>>>(
        pred_boxes, gt_boxes, candd, candn, sel, merge_l1, merge_gio);

    // K3: corrections + partial fold + fused finalize (ticketed)
    correction_kernel<<<BB * 4, 256, 0, stream>>>(
        pred_logits, sel, gt_labels, acc, ticket, out,
        focal_part, merge_l1, merge_gio);
}

// Round 2
// 200.911 us; speedup vs baseline: 1.2375x; 1.0094x over previous
//
#include <hip/hip_runtime.h>
#include <hip/hip_bf16.h>
#include <float.h>

// Problem constants (from setup_inputs): B=16, N=21504, C=80, G=64, K=9
#define BB 16
#define NN 21504
#define CC 80
#define GG 64
#define KK 9
#define NSEG 4
#define SEG4 (NN / 2 / NSEG)   // float4s per segment: 2688
#define T4   (SEG4 / 64)       // 42 float4 iterations per lane

// focal grid: 3360 blocks * 256 threads * 8 float4 = 6,881,280 = B*N*C/4 exactly
#define FB 3360
#define FSTRIDE (FB * 256)
#define TOPKB (BB * GG)        // 1024 top-k blocks in the fused kernel
#define FWAVES (FB * 4)        // 13440 per-wave focal partials

// ---------------- focal helpers ----------------
__device__ __forceinline__ float focal_t0(float x) {
    float ax = fabsf(x);
    float em = __expf(-ax);
    float sp = __logf(1.0f + em);
    float spx = fmaxf(x, 0.0f) + sp;     // softplus(x)
    float r = 1.0f / (1.0f + em);
    float p = (x >= 0.0f) ? r : em * r;  // sigmoid(x)
    return 0.75f * spx * p * p;
}

__device__ __forceinline__ float focal_corr(float x) {
    float ax = fabsf(x);
    float em = __expf(-ax);
    float sp = __logf(1.0f + em);
    float spx = fmaxf(x, 0.0f) + sp;
    float spn = fmaxf(-x, 0.0f) + sp;
    float r = 1.0f / (1.0f + em);
    float p = (x >= 0.0f) ? r : em * r;
    float q = 1.0f - p;
    float f1 = 0.25f * spn * q * q;
    float f0 = 0.75f * spx * p * p;
    return f1 - f0;
}

// one shared distance function so both scans produce bit-identical values
__device__ __forceinline__ float d2f(float cx, float cy, float x, float y) {
    float dx = cx - x, dy = cy - y;
    return dx * dx + dy * dy;
}

// Kernel 1 (FULLY FUSED): blocks [0,1024) = per-pair top-9: 4 waves do the
// 4 segments, candidates meet in LDS (all 4 segments of a pair live in THIS
// block -> the old merge kernel had no cross-block dependency; it is now the
// in-block epilogue, incl. bbox L1+GIoU). Blocks [1024,4384) = focal main
// sum writing per-WAVE partials (no LDS, no syncthreads, no atomics).
__global__ __launch_bounds__(256) void k1_all(
    const float* __restrict__ locations,   // (N,2)
    const float* __restrict__ gt_boxes,    // (B,G,4)
    const float* __restrict__ logits,      // (B,N,C)
    const float* __restrict__ pred_boxes,  // (B,N,4)
    int*   __restrict__ sel,               // (1024*KK)
    double* __restrict__ merge_l1,         // (1024)
    double* __restrict__ merge_gio,        // (1024)
    unsigned long long* __restrict__ hdr,  // 64B header: acc[3] + ticket
    double* __restrict__ focal_part)       // (FWAVES) per-wave partial sums
{
    if (blockIdx.x >= TOPKB) {
        // ---------------- focal role ----------------
        int fb = (int)blockIdx.x - TOPKB;
        const float4* v = (const float4*)logits;
        int tid = fb * 256 + threadIdx.x;

        float4 L0 = v[tid + 0 * FSTRIDE];
        float4 L1 = v[tid + 1 * FSTRIDE];
        float4 L2 = v[tid + 2 * FSTRIDE];
        float4 L3 = v[tid + 3 * FSTRIDE];
        float4 L4 = v[tid + 4 * FSTRIDE];
        float4 L5 = v[tid + 5 * FSTRIDE];
        float4 L6 = v[tid + 6 * FSTRIDE];
        float4 L7 = v[tid + 7 * FSTRIDE];

        float s0 = 0.f, s1 = 0.f, s2 = 0.f, s3 = 0.f;
        s0 += focal_t0(L0.x); s1 += focal_t0(L0.y); s2 += focal_t0(L0.z); s3 += focal_t0(L0.w);
        s0 += focal_t0(L1.x); s1 += focal_t0(L1.y); s2 += focal_t0(L1.z); s3 += focal_t0(L1.w);
        s0 += focal_t0(L2.x); s1 += focal_t0(L2.y); s2 += focal_t0(L2.z); s3 += focal_t0(L2.w);
        s0 += focal_t0(L3.x); s1 += focal_t0(L3.y); s2 += focal_t0(L3.z); s3 += focal_t0(L3.w);
        s0 += focal_t0(L4.x); s1 += focal_t0(L4.y); s2 += focal_t0(L4.z); s3 += focal_t0(L4.w);
        s0 += focal_t0(L5.x); s1 += focal_t0(L5.y); s2 += focal_t0(L5.z); s3 += focal_t0(L5.w);
        s0 += focal_t0(L6.x); s1 += focal_t0(L6.y); s2 += focal_t0(L6.z); s3 += focal_t0(L6.w);
        s0 += focal_t0(L7.x); s1 += focal_t0(L7.y); s2 += focal_t0(L7.z); s3 += focal_t0(L7.w);

        double d = (double)((s0 + s1) + (s2 + s3));
#pragma unroll
        for (int o = 32; o > 0; o >>= 1) d += __shfl_down(d, o);
        if ((threadIdx.x & 63) == 0)
            focal_part[fb * 4 + (threadIdx.x >> 6)] = d;
        return;
    }

    // ---------------- top-k role ----------------
    if (blockIdx.x == 0 && threadIdx.x < 8) hdr[threadIdx.x] = 0ull;

    __shared__ float lds_d[NSEG * KK];
    __shared__ int   lds_n[NSEG * KK];

    int seg  = threadIdx.x >> 6;           // 0..3
    int lane = threadIdx.x & 63;
    int pair = blockIdx.x;                 // 0..1023
    int b = pair >> 6;
    int g = pair & (GG - 1);

    const float4 gt = ((const float4*)gt_boxes)[b * GG + g];
    float cx = gt.x, cy = gt.y;
    const float4* loc4 = (const float4*)locations;
    int base4 = seg * SEG4 + lane;

    // Scan 1: per-lane min over 84 points; 6 groups of 7 batched loads
    float m0 = FLT_MAX, m1 = FLT_MAX, m2 = FLT_MAX, m3 = FLT_MAX;
    for (int t = 0; t < T4; t += 7) {
        float4 L0 = loc4[base4 + (t + 0) * 64];
        float4 L1 = loc4[base4 + (t + 1) * 64];
        float4 L2 = loc4[base4 + (t + 2) * 64];
        float4 L3 = loc4[base4 + (t + 3) * 64];
        float4 L4 = loc4[base4 + (t + 4) * 64];
        float4 L5 = loc4[base4 + (t + 5) * 64];
        float4 L6 = loc4[base4 + (t + 6) * 64];
        m0 = fminf(m0, fminf(d2f(cx, cy, L0.x, L0.y), d2f(cx, cy, L0.z, L0.w)));
        m1 = fminf(m1, fminf(d2f(cx, cy, L1.x, L1.y), d2f(cx, cy, L1.z, L1.w)));
        m2 = fminf(m2, fminf(d2f(cx, cy, L2.x, L2.y), d2f(cx, cy, L2.z, L2.w)));
        m3 = fminf(m3, fminf(d2f(cx, cy, L3.x, L3.y), d2f(cx, cy, L3.z, L3.w)));
        m0 = fminf(m0, fminf(d2f(cx, cy, L4.x, L4.y), d2f(cx, cy, L4.z, L4.w)));
        m1 = fminf(m1, fminf(d2f(cx, cy, L5.x, L5.y), d2f(cx, cy, L5.z, L5.w)));
        m2 = fminf(m2, fminf(d2f(cx, cy, L6.x, L6.y), d2f(cx, cy, L6.z, L6.w)));
    }
    float md = fminf(fminf(m0, m1), fminf(m2, m3));

    // T = 9th-smallest lane-min (ties only enlarge T -> superset, safe)
    float v = md;
    float T = FLT_MAX;
    for (int r = 0; r < KK; ++r) {
        float m = v;
        for (int s = 1; s < 64; s <<= 1) m = fminf(m, __shfl_xor(m, s));
        T = m;
        if (v == m) v = FLT_MAX;
    }

    // Scan 2: collect candidates d2 <= T, up to 6 per lane in named scalars
    float sd0 = FLT_MAX, sd1 = FLT_MAX, sd2 = FLT_MAX,
          sd3 = FLT_MAX, sd4 = FLT_MAX, sd5 = FLT_MAX;
    int   sn0 = 0x7fffffff, sn1 = 0x7fffffff, sn2 = 0x7fffffff,
          sn3 = 0x7fffffff, sn4 = 0x7fffffff, sn5 = 0x7fffffff;
    int cnt = 0;
#define PUSH(dv, nv)                                             \
    do {                                                         \
        if (cnt == 0)      { sd0 = dv; sn0 = nv; }               \
        else if (cnt == 1) { sd1 = dv; sn1 = nv; }               \
        else if (cnt == 2) { sd2 = dv; sn2 = nv; }               \
        else if (cnt == 3) { sd3 = dv; sn3 = nv; }               \
        else if (cnt == 4) { sd4 = dv; sn4 = nv; }               \
        else if (cnt == 5) { sd5 = dv; sn5 = nv; }               \
        ++cnt;                                                   \
    } while (0)
#define TEST(Lv, tt)                                             \
    do {                                                         \
        int i4 = base4 + (tt) * 64;                              \
        float da = d2f(cx, cy, Lv.x, Lv.y);                      \
        float db = d2f(cx, cy, Lv.z, Lv.w);                      \
        if (da <= T) PUSH(da, 2 * i4);                           \
        if (db <= T) PUSH(db, 2 * i4 + 1);                       \
    } while (0)

    for (int t = 0; t < T4; t += 7) {
        float4 L0 = loc4[base4 + (t + 0) * 64];
        float4 L1 = loc4[base4 + (t + 1) * 64];
        float4 L2 = loc4[base4 + (t + 2) * 64];
        float4 L3 = loc4[base4 + (t + 3) * 64];
        float4 L4 = loc4[base4 + (t + 4) * 64];
        float4 L5 = loc4[base4 + (t + 5) * 64];
        float4 L6 = loc4[base4 + (t + 6) * 64];
        TEST(L0, t + 0);
        TEST(L1, t + 1);
        TEST(L2, t + 2);
        TEST(L3, t + 3);
        TEST(L4, t + 4);
        TEST(L5, t + 5);
        TEST(L6, t + 6);
    }
#undef TEST
#undef PUSH

    int ovf = (cnt > 6) ? 1 : 0;
    for (int s = 1; s < 64; s <<= 1) ovf = max(ovf, __shfl_xor(ovf, s));

    if (ovf == 0) {
        for (int r = 0; r < KK; ++r) {
            float bv = sd0; int bn = sn0;
            bool c;
            c = sd1 < bv; bv = c ? sd1 : bv; bn = c ? sn1 : bn;
            c = sd2 < bv; bv = c ? sd2 : bv; bn = c ? sn2 : bn;
            c = sd3 < bv; bv = c ? sd3 : bv; bn = c ? sn3 : bn;
            c = sd4 < bv; bv = c ? sd4 : bv; bn = c ? sn4 : bn;
            c = sd5 < bv; bv = c ? sd5 : bv; bn = c ? sn5 : bn;
            for (int s = 1; s < 64; s <<= 1) {
                float ov = __shfl_xor(bv, s);
                int   on = __shfl_xor(bn, s);
                bool cc = (ov < bv) || (ov == bv && on < bn);
                bv = cc ? ov : bv;
                bn = cc ? on : bn;
            }
            if (sn0 == bn) sd0 = FLT_MAX;
            if (sn1 == bn) sd1 = FLT_MAX;
            if (sn2 == bn) sd2 = FLT_MAX;
            if (sn3 == bn) sd3 = FLT_MAX;
            if (sn4 == bn) sd4 = FLT_MAX;
            if (sn5 == bn) sd5 = FLT_MAX;
            if (lane == 0) { lds_d[seg * KK + r] = bv; lds_n[seg * KK + r] = bn; }
        }
    } else {
        // rare exact fallback: 9 lex-min rescans of this segment
        float lastD = -1.0f; int lastN = -1;
        for (int r = 0; r < KK; ++r) {
            float bv = FLT_MAX; int bn = 0x7fffffff;
            for (int t = 0; t < T4; ++t) {
                int i4 = base4 + t * 64;
                float4 A = loc4[i4];
                float da = d2f(cx, cy, A.x, A.y);
                float db = d2f(cx, cy, A.z, A.w);
                int na = 2 * i4, nb = 2 * i4 + 1;
                bool ga = (da > lastD) || (da == lastD && na > lastN);
                bool ca = ga && ((da < bv) || (da == bv && na < bn));
                bv = ca ? da : bv; bn = ca ? na : bn;
                bool gb = (db > lastD) || (db == lastD && nb > lastN);
                bool cb = gb && ((db < bv) || (db == bv && nb < bn));
                bv = cb ? db : bv; bn = cb ? nb : bn;
            }
            for (int s = 1; s < 64; s <<= 1) {
                float ov = __shfl_xor(bv, s);
                int   on = __shfl_xor(bn, s);
                bool cc = (ov < bv) || (ov == bv && on < bn);
                bv = cc ? ov : bv;
                bn = cc ? on : bn;
            }
            lastD = bv; lastN = bn;
            if (lane == 0) { lds_d[seg * KK + r] = bv; lds_n[seg * KK + r] = bn; }
        }
    }

    // -------- in-block merge of 36 candidates + bbox epilogue (wave 0) ----
    __syncthreads();
    if (threadIdx.x < 64) {
        float vd = FLT_MAX; int vn = 0x7fffffff;
        if (lane < NSEG * KK) {
            vd = lds_d[lane];
            vn = lds_n[lane];
        }

        int myn = 0;
        for (int r = 0; r < KK; ++r) {
            float bv = vd; int bn = vn;
            for (int s = 1; s < 64; s <<= 1) {
                float ov = __shfl_xor(bv, s);
                int   on = __shfl_xor(bn, s);
                bool cc = (ov < bv) || (ov == bv && on < bn);
                bv = cc ? ov : bv;
                bn = cc ? on : bn;
            }
            if (vn == bn) vd = FLT_MAX;   // n unique across lanes
            if (lane == r) myn = bn;
            if (lane == 0) sel[pair * KK + r] = bn;
        }
        myn = myn < 0 ? 0 : (myn >= NN ? NN - 1 : myn);  // fault guard

        float l1 = 0.0f, gio = 0.0f;
        if (lane < KK) {
            float4 p = ((const float4*)pred_boxes)[b * NN + myn];
            l1 = fabsf(p.x - gt.x) + fabsf(p.y - gt.y) + fabsf(p.z - gt.z) + fabsf(p.w - gt.w);

            float ax1 = p.x - 0.5f * p.z, ay1 = p.y - 0.5f * p.w;
            float ax2 = p.x + 0.5f * p.z, ay2 = p.y + 0.5f * p.w;
            float bx1 = gt.x - 0.5f * gt.z, by1 = gt.y - 0.5f * gt.w;
            float bx2 = gt.x + 0.5f * gt.z, by2 = gt.y + 0.5f * gt.w;

            float area_a = (ax2 - ax1) * (ay2 - ay1);
            float area_b = (bx2 - bx1) * (by2 - by1);
            float ix1 = fmaxf(ax1, bx1), iy1 = fmaxf(ay1, by1);
            float ix2 = fminf(ax2, bx2), iy2 = fminf(ay2, by2);
            float iw = fmaxf(ix2 - ix1, 0.0f), ih = fmaxf(iy2 - iy1, 0.0f);
            float inter = iw * ih;
            float uni = area_a + area_b - inter;
            float iou = inter / uni;
            float ccx1 = fminf(ax1, bx1), ccy1 = fminf(ay1, by1);
            float ccx2 = fmaxf(ax2, bx2), ccy2 = fmaxf(ay2, by2);
            float cw = fmaxf(ccx2 - ccx1, 0.0f), ch = fmaxf(ccy2 - ccy1, 0.0f);
            float ac = cw * ch;
            float giou = iou - (ac - uni) / ac;
            gio = 1.0f - giou;
        }
        for (int o = 32; o > 0; o >>= 1) {
            l1 += __shfl_down(l1, o);
            gio += __shfl_down(gio, o);
        }
        if (lane == 0) {
            merge_l1[pair]  = (double)l1;
            merge_gio[pair] = (double)gio;
        }
    }
}

// Kernel 2: dedup + correction + partial-sum fold + FUSED finalize via
// device-atomic ticket. Each of the 64 blocks folds disjoint slices of the
// focal/merge partials on LANES (parallel gathers folded into the shuffle
// reductions — no serial thread-0 L2-latency chain). Contended atomics: 64x3.
#define EPB 144   // elements per block (576 / 4)
__global__ __launch_bounds__(256) void correction_kernel(
    const float* __restrict__ logits, const int* __restrict__ sel,
    const int* __restrict__ gt_labels, double* __restrict__ acc,
    int* __restrict__ ticket, float* __restrict__ out,
    const double* __restrict__ focal_part,
    const double* __restrict__ merge_l1,
    const double* __restrict__ merge_gio)
{
    int bq = blockIdx.x;           // 0..63
    int b  = bq >> 2;              // image
    int q  = bq & 3;               // quarter
    int wv = threadIdx.x >> 6;
    int ln = threadIdx.x & 63;

    __shared__ int keys[GG * KK];
    for (int e = threadIdx.x; e < GG * KK; e += blockDim.x) {
        int g = e / KK;
        int n = sel[(b * GG + g) * KK + (e - g * KK)];
        keys[e] = n * CC + gt_labels[b * GG + g];
    }
    __syncthreads();

    bool active = (threadIdx.x < EPB);
    int e = q * EPB + (active ? threadIdx.x : 0);   // bounded index
    int k = keys[e];
    k = active ? k : -1;                            // -1 never matches

    // branch-free duplicate test, 8 pipelined LDS reads per group
    int dup = 0;
    for (int e2 = 0; e2 < GG * KK; e2 += 8) {
        int k0 = keys[e2 + 0];
        int k1 = keys[e2 + 1];
        int k2 = keys[e2 + 2];
        int k3 = keys[e2 + 3];
        int k4 = keys[e2 + 4];
        int k5 = keys[e2 + 5];
        int k6 = keys[e2 + 6];
        int k7 = keys[e2 + 7];
        int h = 0;
        h |= (int)(k0 == k) & (int)(e2 + 0 < e);
        h |= (int)(k1 == k) & (int)(e2 + 1 < e);
        h |= (int)(k2 == k) & (int)(e2 + 2 < e);
        h |= (int)(k3 == k) & (int)(e2 + 3 < e);
        h |= (int)(k4 == k) & (int)(e2 + 4 < e);
        h |= (int)(k5 == k) & (int)(e2 + 5 < e);
        h |= (int)(k6 == k) & (int)(e2 + 6 < e);
        h |= (int)(k7 == k) & (int)(e2 + 7 < e);
        dup |= h;
    }

    float corr = 0.0f;
    if (active && dup == 0) {
        corr = focal_corr(logits[(long long)b * NN * CC + k]);
    }

    double d = (double)corr;
    // fold this block's slice of the focal per-wave partials:
    // FWAVES=13440 = 64 blocks x 210; entry = bq + t*64, t in [0,210).
    if (threadIdx.x < 210) d += focal_part[bq + (threadIdx.x << 6)];

    // fold this block's 16 merge partials on waves 1 (l1) and 2 (gio)
    double s1 = 0.0, s2 = 0.0;
    if (wv == 1 && ln < 16) s1 = merge_l1[bq * 16 + ln];
    if (wv == 2 && ln < 16) s2 = merge_gio[bq * 16 + ln];

#pragma unroll
    for (int o = 32; o > 0; o >>= 1) {
        d  += __shfl_down(d, o);
        s1 += __shfl_down(s1, o);
        s2 += __shfl_down(s2, o);
    }
    __shared__ double wsum[4], ws1[4], ws2[4];
    if (ln == 0) { wsum[wv] = d; ws1[wv] = s1; ws2[wv] = s2; }
    __syncthreads();
    __shared__ int amlast;
    if (threadIdx.x == 0) {
        atomicAdd(&acc[0], wsum[0] + wsum[1] + wsum[2] + wsum[3]);
        atomicAdd(&acc[1], ws1[0] + ws1[1] + ws1[2] + ws1[3]);
        atomicAdd(&acc[2], ws2[0] + ws2[1] + ws2[2] + ws2[3]);
        __threadfence();                       // my adds visible before ticket
        int t = atomicAdd(ticket, 1);
        amlast = (t == (int)gridDim.x - 1) ? 1 : 0;
    }
    __syncthreads();
    if (threadIdx.x == 0 && amlast) {
        double a0 = atomicAdd(&acc[0], 0.0);
        double a1 = atomicAdd(&acc[1], 0.0);
        double a2 = atomicAdd(&acc[2], 0.0);
        out[0] = (float)(a0 / (double)((long long)BB * NN * CC));
        out[1] = (float)(a1 / (double)(BB * GG * KK * 4));
        out[2] = (float)(a2 / (double)(BB * GG * KK));
    }
}

extern "C" void kernel_launch(void* const* d_in, const int* in_sizes, int n_in,
                              void* d_out, int out_size, void* d_ws, size_t ws_size,
                              hipStream_t stream) {
    const float* pred_logits = (const float*)d_in[0];  // (B,N,C)
    const float* pred_boxes  = (const float*)d_in[1];  // (B,N,4)
    const float* locations   = (const float*)d_in[2];  // (N,2)
    const float* gt_boxes    = (const float*)d_in[3];  // (B,G,4)
    const int*   gt_labels   = (const int*)d_in[4];    // (B,G)
    float* out = (float*)d_out;

    // workspace layout:
    //   [0,64)            header: acc[3] doubles + ticket int (at 24) + pad
    //   [64,36928)        sel        1024*9 ints
    //   [36928,45120)     merge_l1   1024 doubles
    //   [45120,53312)     merge_gio  1024 doubles
    //   [53312,160832)    focal_part 13440 doubles (per-wave)
    unsigned long long* hdr = (unsigned long long*)d_ws;
    double* acc    = (double*)d_ws;
    int*    ticket = (int*)((char*)d_ws + 24);
    int*    sel    = (int*)((char*)d_ws + 64);
    double* merge_l1   = (double*)((char*)d_ws + 36928);
    double* merge_gio  = (double*)((char*)d_ws + 45120);
    double* focal_part = (double*)((char*)d_ws + 53312);

    // K1: fused top-k (blocks 0..1023, incl. in-block merge + bbox epilogue)
    //     + focal per-wave partials (blocks 1024..4383)
    k1_all<<<TOPKB + FB, 256, 0, stream>>>(
        locations, gt_boxes, pred_logits, pred_boxes,
        sel, merge_l1, merge_gio, hdr, focal_part);

    // K2: corrections + partial folds + fused finalize (ticketed)
    correction_kernel<<<BB * 4, 256, 0, stream>>>(
        pred_logits, sel, gt_labels, acc, ticket, out,
        focal_part, merge_l1, merge_gio);
}